// Round 6
// baseline (603.870 us; speedup 1.0000x reference)
//
#include <hip/hip_runtime.h>
#include <math.h>

__device__ __forceinline__ float lrelu(float x){ return x > 0.0f ? x : 0.2f*x; }
__device__ __forceinline__ float bcastf(float v, int l){
    return __int_as_float(__builtin_amdgcn_readlane(__float_as_int(v), l));
}
__device__ __forceinline__ float wsum(float v){
    #pragma unroll
    for(int off=32; off; off>>=1) v += __shfl_xor(v, off, 64);
    return v;
}

// ---------------- precompute ----------------

__global__ void k_count(const int* __restrict__ dst, int* __restrict__ cnt, int E){
    int e = blockIdx.x*256 + threadIdx.x;
    if(e < E) atomicAdd(&cnt[dst[e]], 1);
}

__global__ __launch_bounds__(1024) void k_scan(const int* __restrict__ cnt, int* __restrict__ rowptr, int n){
    __shared__ int ws[16];
    __shared__ int carrysh;
    int t = threadIdx.x, lane = t & 63, wv = t >> 6;
    if(t==0){ carrysh = 0; rowptr[0] = 0; }
    __syncthreads();
    for(int base=0; base<n; base+=1024){
        int i = base + t;
        int v = (i<n) ? cnt[i] : 0;
        int s = v;
        #pragma unroll
        for(int off=1; off<64; off<<=1){ int u = __shfl_up(s, off, 64); if(lane>=off) s += u; }
        if(lane==63) ws[wv] = s;
        __syncthreads();
        if(t < 16){
            int u = ws[t];
            #pragma unroll
            for(int off=1; off<16; off<<=1){ int u2 = __shfl_up(u, off, 16); if(t>=off) u += u2; }
            ws[t] = u;
        }
        __syncthreads();
        int carry = carrysh;
        int wbase = wv ? ws[wv-1] : 0;
        if(i<n) rowptr[i+1] = carry + wbase + s;
        int total = ws[15];
        __syncthreads();
        if(t==0) carrysh = carry + total;
        __syncthreads();
    }
}

__global__ void k_scatter(const int* __restrict__ dst, const int* __restrict__ rowptr,
                          int* __restrict__ cnt2, int* __restrict__ eid, int E){
    int e = blockIdx.x*256 + threadIdx.x;
    if(e >= E) return;
    int d = dst[e];
    int p = rowptr[d] + atomicAdd(&cnt2[d], 1);
    eid[p] = e;
}

__global__ __launch_bounds__(256) void k_sortb(const int* __restrict__ rowptr, int* __restrict__ eid, int n){
    int node = blockIdx.x*4 + (threadIdx.x>>6);
    if(node >= n) return;
    int lane = threadIdx.x & 63;
    int b = rowptr[node], e = rowptr[node+1];
    int nj = e - b;
    if(nj <= 1) return;
    if(nj <= 64){
        int v = (lane < nj) ? eid[b+lane] : 0x7fffffff;
        for(int k=2; k<=64; k<<=1){
            for(int j=k>>1; j>0; j>>=1){
                int vv = __shfl_xor(v, j, 64);
                bool up = ((lane & k) == 0);
                bool lower = ((lane & j) == 0);
                int mn = min(v,vv), mx = max(v,vv);
                v = (lower == up) ? mn : mx;
            }
        }
        if(lane < nj) eid[b+lane] = v;
    } else if(lane == 0){
        for(int i=b+1; i<e; i++){
            int key = eid[i]; int j = i-1;
            while(j>=b && eid[j] > key){ eid[j+1] = eid[j]; j--; }
            eid[j+1] = key;
        }
    }
}

// pack src + edge-attr index per CSR slot
__global__ void k_pack(const int* __restrict__ eid, const int* __restrict__ src,
                       const int* __restrict__ eattr, int* __restrict__ packed, int E){
    int p = blockIdx.x*256 + threadIdx.x;
    if(p >= E) return;
    int e = eid[p];
    packed[p] = src[e] | (eattr[e] << 17);
}

// T[l][a] = emb[a] . wvec[l]   (wvec[l][k] = sum_c We[l][k][c]*atte[l][c])
__global__ __launch_bounds__(768) void k_table(const float* __restrict__ We, const float* __restrict__ atte,
                                               const float* __restrict__ emb, float* __restrict__ T){
    __shared__ float wv[768];
    int t = threadIdx.x;
    {
        int l = t>>7, k = t&127;
        const float* w = We + ((size_t)l*128 + k)*64;
        const float* a = atte + l*64;
        float s = 0.f;
        #pragma unroll 8
        for(int c=0;c<64;c++) s += w[c]*a[c];
        wv[t] = s;
    }
    __syncthreads();
    int l = t>>7, a = t&127;
    const float4* er = (const float4*)(emb + (size_t)a*128);
    const float* w = wv + l*128;
    float acc = 0.f;
    for(int k=0;k<32;k++){
        float4 v = er[k];
        acc += v.x*w[k*4+0] + v.y*w[k*4+1] + v.z*w[k*4+2] + v.w*w[k*4+3];
    }
    T[l*128 + a] = acc;
}

// ---------------- layer-0 h: lane=channel, wave owns 8 nodes, registers only ----------------

__global__ __launch_bounds__(256) void k_hx(const int* __restrict__ xidx, const float* __restrict__ emb,
        const float* __restrict__ W, const float* __restrict__ atts, const float* __restrict__ attd,
        float* __restrict__ h, float* __restrict__ as_, float* __restrict__ ad_, int n){
    int t = threadIdx.x, lane = t & 63;
    int base = blockIdx.x*32 + (t>>6)*8;
    if(base >= n) return;
    int nv = min(8, n - base);

    float xv0[8], xv1[8];
    #pragma unroll
    for(int nn=0;nn<8;nn++){
        if(nn < nv){
            int xi = xidx[base+nn];
            xv0[nn] = emb[(size_t)xi*128 + lane];
            xv1[nn] = emb[(size_t)xi*128 + 64 + lane];
        } else { xv0[nn]=0.f; xv1[nn]=0.f; }
    }
    float hv[8] = {0,0,0,0,0,0,0,0};
    #pragma unroll 2
    for(int k=0;k<64;k++){
        float w = W[k*64 + lane];
        #pragma unroll
        for(int nn=0;nn<8;nn++) hv[nn] = fmaf(bcastf(xv0[nn],k), w, hv[nn]);
    }
    #pragma unroll 2
    for(int k=0;k<64;k++){
        float w = W[(k+64)*64 + lane];
        #pragma unroll
        for(int nn=0;nn<8;nn++) hv[nn] = fmaf(bcastf(xv1[nn],k), w, hv[nn]);
    }
    float atl = atts[lane], adl = attd[lane];
    #pragma unroll
    for(int nn=0;nn<8;nn++){
        float sa = wsum(hv[nn]*atl);
        float sd = wsum(hv[nn]*adl);
        if(nn < nv){
            h[(size_t)(base+nn)*64 + lane] = hv[nn];
            if(lane==0){ as_[base+nn] = sa; ad_[base+nn] = sd; }
        }
    }
}

// ---------------- GAT aggregation: wave per node, table-lookup a_e ----------------

__global__ __launch_bounds__(256) void k_gat(const float* __restrict__ h,
        const float* __restrict__ as_, const float* __restrict__ ad_,
        const float* __restrict__ T, const int* __restrict__ packed,
        const int* __restrict__ rowptr, const float* __restrict__ bias,
        float* __restrict__ o, int n){
    __shared__ float Tl[128];
    if(threadIdx.x < 128) Tl[threadIdx.x] = T[threadIdx.x];
    __syncthreads();
    int node = blockIdx.x*4 + (threadIdx.x>>6);
    if(node >= n) return;
    int lane = threadIdx.x & 63;
    int b = rowptr[node], e = rowptr[node+1];
    float adv = ad_[node];
    float m = -1e30f, d = 0.f, sumae = 0.f;
    float a0=0.f, a1=0.f, a2=0.f, a3=0.f;
    for(int j0=b; j0<e; j0+=64){
        int nj = min(64, e-j0);
        int sj = 0; float aev = 0.f, lg = -1e30f;
        if(lane < nj){
            int pk = packed[j0+lane];
            sj  = pk & 0x1FFFF;
            aev = Tl[pk >> 17];
            lg  = lrelu(as_[sj] + adv + aev);
        }
        float cm = lg, sa = aev;
        #pragma unroll
        for(int off=32; off; off>>=1){ cm = fmaxf(cm, __shfl_xor(cm,off,64)); sa += __shfl_xor(sa,off,64); }
        sumae += sa;
        float nm = fmaxf(m, cm);
        float w = (lane<nj) ? expf(lg-nm) : 0.f;
        float ws = w;
        #pragma unroll
        for(int off=32; off; off>>=1) ws += __shfl_xor(ws,off,64);
        float scale = (m > -1e29f) ? expf(m-nm) : 0.f;
        d = d*scale + ws;
        a0*=scale; a1*=scale; a2*=scale; a3*=scale;
        int j = 0;
        for(; j+3<nj; j+=4){
            a0 = fmaf(bcastf(w,j+0), h[(size_t)__builtin_amdgcn_readlane(sj,j+0)*64 + lane], a0);
            a1 = fmaf(bcastf(w,j+1), h[(size_t)__builtin_amdgcn_readlane(sj,j+1)*64 + lane], a1);
            a2 = fmaf(bcastf(w,j+2), h[(size_t)__builtin_amdgcn_readlane(sj,j+2)*64 + lane], a2);
            a3 = fmaf(bcastf(w,j+3), h[(size_t)__builtin_amdgcn_readlane(sj,j+3)*64 + lane], a3);
        }
        for(; j<nj; j++)
            a0 = fmaf(bcastf(w,j), h[(size_t)__builtin_amdgcn_readlane(sj,j)*64 + lane], a0);
        m = nm;
    }
    int deg = e - b;
    float ael = sumae / fmaxf((float)deg, 1.f);
    float ls = lrelu(as_[node] + adv + ael);
    float nm = fmaxf(m, ls);
    float scale = (m > -1e29f) ? expf(m-nm) : 0.f;
    float wl = expf(ls-nm);
    d = d*scale + wl;
    float acc = (a0+a1)+(a2+a3);
    acc = acc*scale + wl*h[(size_t)node*64 + lane];
    o[(size_t)node*64 + lane] = acc/d + bias[lane];
}

// ---------------- dense: lane=channel, wave owns 8 nodes, no LDS, no barriers ----------------

__global__ __launch_bounds__(256) void k_dense(
    const float* __restrict__ o,
    const float* __restrict__ W1, const float* __restrict__ b1,
    const float* __restrict__ W2, const float* __restrict__ b2,
    const float* __restrict__ W3, const float* __restrict__ b3,
    float* __restrict__ bestF, float* __restrict__ bestMs, int layer,
    const float* __restrict__ Wn, const float* __restrict__ atts, const float* __restrict__ attd,
    float* __restrict__ hn, float* __restrict__ asn, float* __restrict__ adn_,
    const float* __restrict__ A, const float* __restrict__ g1b1,
    const float* __restrict__ w2, const float* __restrict__ g1b2,
    const float* __restrict__ B, const float* __restrict__ g2b1,
    const float* __restrict__ C, const float* __restrict__ g2b2,
    float* __restrict__ h1, float* __restrict__ h2,
    int n, int last)
{
    int t = threadIdx.x, lane = t & 63;
    int base = blockIdx.x*32 + (t>>6)*8;
    if(base >= n) return;
    int nv = min(8, n - base);

    // ---- load o rows: lane = channel
    float ov[8];
    #pragma unroll
    for(int nn=0;nn<8;nn++) ov[nn] = (nn<nv) ? o[(size_t)(base+nn)*64 + lane] : 0.f;

    // ---- B: t1 = relu(o @ W1 + b1)
    float t1[8];
    {
        float bb = b1[lane];
        #pragma unroll
        for(int nn=0;nn<8;nn++) t1[nn] = bb;
        #pragma unroll 4
        for(int k=0;k<64;k++){
            float w = W1[k*64 + lane];
            #pragma unroll
            for(int nn=0;nn<8;nn++) t1[nn] = fmaf(bcastf(ov[nn],k), w, t1[nn]);
        }
        #pragma unroll
        for(int nn=0;nn<8;nn++) t1[nn] = fmaxf(t1[nn], 0.f);
    }

    // ---- C: t2 = relu(t1 @ W2 + b2)
    float t2[8];
    {
        float bb = b2[lane];
        #pragma unroll
        for(int nn=0;nn<8;nn++) t2[nn] = bb;
        #pragma unroll 4
        for(int k=0;k<64;k++){
            float w = W2[k*64 + lane];
            #pragma unroll
            for(int nn=0;nn<8;nn++) t2[nn] = fmaf(bcastf(t1[nn],k), w, t2[nn]);
        }
        #pragma unroll
        for(int nn=0;nn<8;nn++) t2[nn] = fmaxf(t2[nn], 0.f);
    }

    // ---- D: x' = t2 @ W3 + b3 (128 out: c=lane and c=lane+64)
    float xp0[8], xp1[8];
    {
        float ba = b3[lane], bb = b3[lane+64];
        #pragma unroll
        for(int nn=0;nn<8;nn++){ xp0[nn]=ba; xp1[nn]=bb; }
        #pragma unroll 2
        for(int k=0;k<64;k++){
            float w0 = C ? 0.f : 0.f; // (placeholder removed below)
            (void)w0;
            float wa = W3[k*128 + lane];
            float wb = W3[k*128 + 64 + lane];
            #pragma unroll
            for(int nn=0;nn<8;nn++){
                float s = bcastf(t2[nn],k);
                xp0[nn] = fmaf(s, wa, xp0[nn]);
                xp1[nn] = fmaf(s, wb, xp1[nn]);
            }
        }
    }

    // ---- JKN: ms per node, update decision
    float msv[8]; bool upd[8];
    #pragma unroll
    for(int nn=0;nn<8;nn++){
        float p = wsum(xp0[nn]*xp0[nn] + xp1[nn]*xp1[nn]);
        msv[nn] = p;
        float prev = -1e30f;
        if(layer > 0 && nn < nv) prev = bestMs[base+nn];
        upd[nn] = (layer==0) || (p > prev);
    }

    if(!last){
        #pragma unroll
        for(int nn=0;nn<8;nn++){
            if(nn<nv && upd[nn]){
                bestF[(size_t)(base+nn)*128 + lane]      = xp0[nn];
                bestF[(size_t)(base+nn)*128 + 64 + lane] = xp1[nn];
                if(lane==0) bestMs[base+nn] = msv[nn];
            }
        }
        // ---- F: h_next = x' @ Wn (k = 128)
        float hv[8] = {0,0,0,0,0,0,0,0};
        #pragma unroll 2
        for(int k=0;k<64;k++){
            float w = Wn[k*64 + lane];
            #pragma unroll
            for(int nn=0;nn<8;nn++) hv[nn] = fmaf(bcastf(xp0[nn],k), w, hv[nn]);
        }
        #pragma unroll 2
        for(int k=0;k<64;k++){
            float w = Wn[(k+64)*64 + lane];
            #pragma unroll
            for(int nn=0;nn<8;nn++) hv[nn] = fmaf(bcastf(xp1[nn],k), w, hv[nn]);
        }
        float atl = atts[lane], adl = attd[lane];
        #pragma unroll
        for(int nn=0;nn<8;nn++){
            float sa = wsum(hv[nn]*atl);
            float sd = wsum(hv[nn]*adl);
            if(nn<nv){
                hn[(size_t)(base+nn)*64 + lane] = hv[nn];
                if(lane==0){ asn[base+nn] = sa; adn_[base+nn] = sd; }
            }
        }
        return;
    }

    // ================= last layer: fused pooling, feature = upd ? x' : bestF =================
    #pragma unroll
    for(int nn=0;nn<8;nn++){
        if(nn<nv && !upd[nn]){
            xp0[nn] = bestF[(size_t)(base+nn)*128 + lane];
            xp1[nn] = bestF[(size_t)(base+nn)*128 + 64 + lane];
        }
    }
    // ---- P1: p1 = relu(F @ g1W1 + g1b1); h1 = p1 . g1W2 + g1b2
    {
        float p1[8];
        float bb = g1b1[lane];
        #pragma unroll
        for(int nn=0;nn<8;nn++) p1[nn] = bb;
        #pragma unroll 2
        for(int k=0;k<64;k++){
            float w = A[k*64 + lane];
            #pragma unroll
            for(int nn=0;nn<8;nn++) p1[nn] = fmaf(bcastf(xp0[nn],k), w, p1[nn]);
        }
        #pragma unroll 2
        for(int k=0;k<64;k++){
            float w = A[(k+64)*64 + lane];
            #pragma unroll
            for(int nn=0;nn<8;nn++) p1[nn] = fmaf(bcastf(xp1[nn],k), w, p1[nn]);
        }
        float w2l = w2[lane], bout = g1b2[0];
        #pragma unroll
        for(int nn=0;nn<8;nn++){
            float s = wsum(fmaxf(p1[nn],0.f)*w2l);
            if(nn<nv && lane==0) h1[base+nn] = s + bout;
        }
    }
    // ---- P2: p2 = relu(F @ g2W1 + g2b1)
    float p2[8];
    {
        float bb = g2b1[lane];
        #pragma unroll
        for(int nn=0;nn<8;nn++) p2[nn] = bb;
        #pragma unroll 2
        for(int k=0;k<64;k++){
            float w = B[k*64 + lane];
            #pragma unroll
            for(int nn=0;nn<8;nn++) p2[nn] = fmaf(bcastf(xp0[nn],k), w, p2[nn]);
        }
        #pragma unroll 2
        for(int k=0;k<64;k++){
            float w = B[(k+64)*64 + lane];
            #pragma unroll
            for(int nn=0;nn<8;nn++) p2[nn] = fmaf(bcastf(xp1[nn],k), w, p2[nn]);
        }
        #pragma unroll
        for(int nn=0;nn<8;nn++) p2[nn] = fmaxf(p2[nn], 0.f);
    }
    // ---- P3: h2 = p2 @ g2W2 + g2b2 (128 out)
    {
        float r0[8], r1[8];
        float ba = g2b2[lane], bb = g2b2[lane+64];
        #pragma unroll
        for(int nn=0;nn<8;nn++){ r0[nn]=ba; r1[nn]=bb; }
        #pragma unroll 2
        for(int k=0;k<64;k++){
            float wa = C[k*128 + lane];
            float wb = C[k*128 + 64 + lane];
            #pragma unroll
            for(int nn=0;nn<8;nn++){
                float s = bcastf(p2[nn],k);
                r0[nn] = fmaf(s, wa, r0[nn]);
                r1[nn] = fmaf(s, wb, r1[nn]);
            }
        }
        #pragma unroll
        for(int nn=0;nn<8;nn++){
            if(nn<nv){
                h2[(size_t)(base+nn)*128 + lane]      = r0[nn];
                h2[(size_t)(base+nn)*128 + 64 + lane] = r1[nn];
            }
        }
    }
}

// ---------------- pooling softmax + per-graph prediction MLP ----------------

__global__ __launch_bounds__(128) void k_pool2(const float* __restrict__ h1, const float* __restrict__ h2,
                      float* __restrict__ wbuf,
                      const float* __restrict__ pW1, const float* __restrict__ pb1,
                      const float* __restrict__ pW2, const float* __restrict__ pb2,
                      const float* __restrict__ pW3, const float* __restrict__ pb3,
                      float* __restrict__ out, int n, int G){
    __shared__ float sh[128];
    __shared__ float hgrow[128];
    int g = blockIdx.x, tid = threadIdx.x;
    int start = (g*n + G-1)/G, end = ((g+1)*n + G-1)/G;
    float lm = -1e30f;
    for(int i=start+tid; i<end; i+=128) lm = fmaxf(lm, h1[i]);
    sh[tid]=lm; __syncthreads();
    for(int off=64; off; off>>=1){ if(tid<off) sh[tid]=fmaxf(sh[tid],sh[tid+off]); __syncthreads(); }
    float m = sh[0]; __syncthreads();
    float lsum = 0.f;
    for(int i=start+tid; i<end; i+=128){ float w = expf(h1[i]-m); wbuf[i]=w; lsum+=w; }
    sh[tid]=lsum; __syncthreads();
    for(int off=64; off; off>>=1){ if(tid<off) sh[tid]+=sh[tid+off]; __syncthreads(); }
    float denom = sh[0];
    float a0=0.f,a1=0.f,a2=0.f,a3=0.f;
    int i = start;
    for(; i+3<end; i+=4){
        a0 = fmaf(wbuf[i+0], h2[(size_t)(i+0)*128 + tid], a0);
        a1 = fmaf(wbuf[i+1], h2[(size_t)(i+1)*128 + tid], a1);
        a2 = fmaf(wbuf[i+2], h2[(size_t)(i+2)*128 + tid], a2);
        a3 = fmaf(wbuf[i+3], h2[(size_t)(i+3)*128 + tid], a3);
    }
    for(; i<end; i++) a0 = fmaf(wbuf[i], h2[(size_t)i*128 + tid], a0);
    float acc = (a0+a1)+(a2+a3);
    hgrow[tid] = acc/denom/(float)(end-start);
    __syncthreads();
    if(tid < 64){
        float t1v = pb1[tid];
        for(int k=0;k<128;k++) t1v = fmaf(hgrow[k], pW1[k*64+tid], t1v);
        t1v = fmaxf(t1v, 0.f);
        float t2v = pb2[tid];
        for(int k=0;k<64;k++) t2v = fmaf(__shfl(t1v,k,64), pW2[k*64+tid], t2v);
        t2v = fmaxf(t2v, 0.f);
        float s = t2v * pW3[tid];
        #pragma unroll
        for(int off=32; off; off>>=1) s += __shfl_xor(s,off,64);
        if(tid==0) out[g] = s + pb3[0];
    }
}

extern "C" void kernel_launch(void* const* d_in, const int* in_sizes, int n_in,
                              void* d_out, int out_size, void* d_ws, size_t ws_size,
                              hipStream_t stream){
    const int*   x_idx   = (const int*)  d_in[0];
    const int*   eindex  = (const int*)  d_in[1];
    const int*   eattr   = (const int*)  d_in[2];
    const float* emb     = (const float*)d_in[4];
    const float* conv_W  = (const float*)d_in[5];
    const float* conv_We = (const float*)d_in[6];
    const float* att_src = (const float*)d_in[7];
    const float* att_dst = (const float*)d_in[8];
    const float* att_edg = (const float*)d_in[9];
    const float* conv_b  = (const float*)d_in[10];
    const float* mW1 = (const float*)d_in[11]; const float* mb1 = (const float*)d_in[12];
    const float* mW2 = (const float*)d_in[13]; const float* mb2 = (const float*)d_in[14];
    const float* mW3 = (const float*)d_in[15]; const float* mb3 = (const float*)d_in[16];
    const float* g1W1= (const float*)d_in[17]; const float* g1b1= (const float*)d_in[18];
    const float* g1W2= (const float*)d_in[19]; const float* g1b2= (const float*)d_in[20];
    const float* g2W1= (const float*)d_in[21]; const float* g2b1= (const float*)d_in[22];
    const float* g2W2= (const float*)d_in[23]; const float* g2b2= (const float*)d_in[24];
    const float* pW1 = (const float*)d_in[25]; const float* pb1 = (const float*)d_in[26];
    const float* pW2 = (const float*)d_in[27]; const float* pb2 = (const float*)d_in[28];
    const float* pW3 = (const float*)d_in[29]; const float* pb3 = (const float*)d_in[30];

    const int N = in_sizes[0];
    const int E = in_sizes[2];
    const int G = out_size;
    const int* src = eindex;
    const int* dst = eindex + E;
    const int NW = (N + 3) / 4;        // wave-per-node grid (gat)
    const int ND = (N + 31) / 32;      // 8-nodes-per-wave grids (hx, dense)

    char* p = (char*)d_ws;
    auto alloc = [&](size_t bytes)->void*{ void* r = (void*)p; p += (bytes + 255) & ~(size_t)255; return r; };
    float* h      = (float*)alloc((size_t)N*64*4);
    float* o      = (float*)alloc((size_t)N*64*4);
    float* bestF  = (float*)alloc((size_t)N*128*4);
    float* h2buf  = (float*)alloc((size_t)N*128*4);
    float* bestMs = (float*)alloc((size_t)N*4);
    float* as_    = (float*)alloc((size_t)N*4);
    float* ad_    = (float*)alloc((size_t)N*4);
    float* Tbuf   = (float*)alloc(6*128*4);
    float* h1     = (float*)alloc((size_t)N*4);
    int*   cnt    = (int*)  alloc((size_t)N*4);
    int*   cnt2   = (int*)  alloc((size_t)N*4);
    int*   rowptr = (int*)  alloc((size_t)(N+1)*4);
    int*   eid    = (int*)  alloc((size_t)E*4);
    int*   packed = (int*)  alloc((size_t)E*4);

    hipMemsetAsync(cnt,  0, (size_t)N*4, stream);
    hipMemsetAsync(cnt2, 0, (size_t)N*4, stream);

    k_count<<<(E+255)/256, 256, 0, stream>>>(dst, cnt, E);
    k_scan<<<1, 1024, 0, stream>>>(cnt, rowptr, N);
    k_scatter<<<(E+255)/256, 256, 0, stream>>>(dst, rowptr, cnt2, eid, E);
    k_sortb<<<NW, 256, 0, stream>>>(rowptr, eid, N);
    k_pack<<<(E+255)/256, 256, 0, stream>>>(eid, src, eattr, packed, E);
    k_table<<<1, 768, 0, stream>>>(conv_We, att_edg, emb, Tbuf);
    k_hx<<<ND, 256, 0, stream>>>(x_idx, emb, conv_W, att_src, att_dst, h, as_, ad_, N);

    for(int l=0; l<6; l++){
        int last = (l==5) ? 1 : 0;
        const float* Wn   = last ? conv_W  : conv_W  + (size_t)(l+1)*8192;
        const float* atsn = last ? att_src : att_src + (l+1)*64;
        const float* atdn = last ? att_dst : att_dst + (l+1)*64;
        k_gat<<<NW, 256, 0, stream>>>(h, as_, ad_, Tbuf + l*128, packed, rowptr, conv_b + l*64, o, N);
        k_dense<<<ND, 256, 0, stream>>>(o,
            mW1 + (size_t)l*4096, mb1 + l*64, mW2 + (size_t)l*4096, mb2 + l*64,
            mW3 + (size_t)l*8192, mb3 + l*128,
            bestF, bestMs, l,
            Wn, atsn, atdn,
            h, as_, ad_,
            g1W1, g1b1, g1W2, g1b2, g2W1, g2b1, g2W2, g2b2,
            h1, h2buf,
            N, last);
    }

    k_pool2<<<G, 128, 0, stream>>>(h1, h2buf, bestMs,
            pW1, pb1, pW2, pb2, pW3, pb3, (float*)d_out, N, G);
}

// Round 7
// 530.863 us; speedup vs baseline: 1.1375x; 1.1375x over previous
//
#include <hip/hip_runtime.h>
#include <math.h>

__device__ __forceinline__ float lrelu(float x){ return x > 0.0f ? x : 0.2f*x; }
__device__ __forceinline__ float bcastf(float v, int l){
    return __int_as_float(__builtin_amdgcn_readlane(__float_as_int(v), l));
}
__device__ __forceinline__ float wsum(float v){
    #pragma unroll
    for(int off=32; off; off>>=1) v += __shfl_xor(v, off, 64);
    return v;
}

// ---------------- precompute ----------------

__global__ void k_count(const int* __restrict__ dst, int* __restrict__ cnt, int E){
    int e = blockIdx.x*256 + threadIdx.x;
    if(e < E) atomicAdd(&cnt[dst[e]], 1);
}

__global__ __launch_bounds__(1024) void k_scan(const int* __restrict__ cnt, int* __restrict__ rowptr, int n){
    __shared__ int ws[16];
    __shared__ int carrysh;
    int t = threadIdx.x, lane = t & 63, wv = t >> 6;
    if(t==0){ carrysh = 0; rowptr[0] = 0; }
    __syncthreads();
    for(int base=0; base<n; base+=1024){
        int i = base + t;
        int v = (i<n) ? cnt[i] : 0;
        int s = v;
        #pragma unroll
        for(int off=1; off<64; off<<=1){ int u = __shfl_up(s, off, 64); if(lane>=off) s += u; }
        if(lane==63) ws[wv] = s;
        __syncthreads();
        if(t < 16){
            int u = ws[t];
            #pragma unroll
            for(int off=1; off<16; off<<=1){ int u2 = __shfl_up(u, off, 16); if(t>=off) u += u2; }
            ws[t] = u;
        }
        __syncthreads();
        int carry = carrysh;
        int wbase = wv ? ws[wv-1] : 0;
        if(i<n) rowptr[i+1] = carry + wbase + s;
        int total = ws[15];
        __syncthreads();
        if(t==0) carrysh = carry + total;
        __syncthreads();
    }
}

__global__ void k_scatter(const int* __restrict__ dst, const int* __restrict__ rowptr,
                          int* __restrict__ cnt2, int* __restrict__ eid, int E){
    int e = blockIdx.x*256 + threadIdx.x;
    if(e >= E) return;
    int d = dst[e];
    int p = rowptr[d] + atomicAdd(&cnt2[d], 1);
    eid[p] = e;
}

__global__ __launch_bounds__(256) void k_sortb(const int* __restrict__ rowptr, int* __restrict__ eid, int n){
    int node = blockIdx.x*4 + (threadIdx.x>>6);
    if(node >= n) return;
    int lane = threadIdx.x & 63;
    int b = rowptr[node], e = rowptr[node+1];
    int nj = e - b;
    if(nj <= 1) return;
    if(nj <= 64){
        int v = (lane < nj) ? eid[b+lane] : 0x7fffffff;
        for(int k=2; k<=64; k<<=1){
            for(int j=k>>1; j>0; j>>=1){
                int vv = __shfl_xor(v, j, 64);
                bool up = ((lane & k) == 0);
                bool lower = ((lane & j) == 0);
                int mn = min(v,vv), mx = max(v,vv);
                v = (lower == up) ? mn : mx;
            }
        }
        if(lane < nj) eid[b+lane] = v;
    } else if(lane == 0){
        for(int i=b+1; i<e; i++){
            int key = eid[i]; int j = i-1;
            while(j>=b && eid[j] > key){ eid[j+1] = eid[j]; j--; }
            eid[j+1] = key;
        }
    }
}

// pack src + edge-attr index per CSR slot
__global__ void k_pack(const int* __restrict__ eid, const int* __restrict__ src,
                       const int* __restrict__ eattr, int* __restrict__ packed, int E){
    int p = blockIdx.x*256 + threadIdx.x;
    if(p >= E) return;
    int e = eid[p];
    packed[p] = src[e] | (eattr[e] << 17);
}

// T[l][a] = emb[a] . wvec[l]
__global__ __launch_bounds__(768) void k_table(const float* __restrict__ We, const float* __restrict__ atte,
                                               const float* __restrict__ emb, float* __restrict__ T){
    __shared__ float wv[768];
    int t = threadIdx.x;
    {
        int l = t>>7, k = t&127;
        const float* w = We + ((size_t)l*128 + k)*64;
        const float* a = atte + l*64;
        float s = 0.f;
        #pragma unroll 8
        for(int c=0;c<64;c++) s += w[c]*a[c];
        wv[t] = s;
    }
    __syncthreads();
    int l = t>>7, a = t&127;
    const float4* er = (const float4*)(emb + (size_t)a*128);
    const float* w = wv + l*128;
    float acc = 0.f;
    for(int k=0;k<32;k++){
        float4 v = er[k];
        acc += v.x*w[k*4+0] + v.y*w[k*4+1] + v.z*w[k*4+2] + v.w*w[k*4+3];
    }
    T[l*128 + a] = acc;
}

// ---------------- layer-0 h: lane=channel, wave owns 4 nodes ----------------

__global__ __launch_bounds__(256) void k_hx(const int* __restrict__ xidx, const float* __restrict__ emb,
        const float* __restrict__ W, const float* __restrict__ atts, const float* __restrict__ attd,
        float* __restrict__ h, float* __restrict__ as_, float* __restrict__ ad_, int n){
    int t = threadIdx.x, lane = t & 63;
    int base = blockIdx.x*16 + (t>>6)*4;
    if(base >= n) return;
    int nv = min(4, n - base);

    float xv0[4], xv1[4];
    #pragma unroll
    for(int nn=0;nn<4;nn++){
        if(nn < nv){
            int xi = xidx[base+nn];
            xv0[nn] = emb[(size_t)xi*128 + lane];
            xv1[nn] = emb[(size_t)xi*128 + 64 + lane];
        } else { xv0[nn]=0.f; xv1[nn]=0.f; }
    }
    float hv[4] = {0,0,0,0};
    #pragma unroll 8
    for(int k=0;k<64;k++){
        float w = W[k*64 + lane];
        #pragma unroll
        for(int nn=0;nn<4;nn++) hv[nn] = fmaf(bcastf(xv0[nn],k), w, hv[nn]);
    }
    #pragma unroll 8
    for(int k=0;k<64;k++){
        float w = W[(k+64)*64 + lane];
        #pragma unroll
        for(int nn=0;nn<4;nn++) hv[nn] = fmaf(bcastf(xv1[nn],k), w, hv[nn]);
    }
    float atl = atts[lane], adl = attd[lane];
    #pragma unroll
    for(int nn=0;nn<4;nn++){
        float sa = wsum(hv[nn]*atl);
        float sd = wsum(hv[nn]*adl);
        if(nn < nv){
            h[(size_t)(base+nn)*64 + lane] = hv[nn];
            if(lane==0){ as_[base+nn] = sa; ad_[base+nn] = sd; }
        }
    }
}

// ---------------- GAT aggregation: wave per node, table-lookup a_e ----------------

__global__ __launch_bounds__(256) void k_gat(const float* __restrict__ h,
        const float* __restrict__ as_, const float* __restrict__ ad_,
        const float* __restrict__ T, const int* __restrict__ packed,
        const int* __restrict__ rowptr, const float* __restrict__ bias,
        float* __restrict__ o, int n){
    __shared__ float Tl[128];
    if(threadIdx.x < 128) Tl[threadIdx.x] = T[threadIdx.x];
    __syncthreads();
    int node = blockIdx.x*4 + (threadIdx.x>>6);
    if(node >= n) return;
    int lane = threadIdx.x & 63;
    int b = rowptr[node], e = rowptr[node+1];
    float adv = ad_[node];
    float m = -1e30f, d = 0.f, sumae = 0.f;
    float a0=0.f, a1=0.f, a2=0.f, a3=0.f;
    for(int j0=b; j0<e; j0+=64){
        int nj = min(64, e-j0);
        int sj = 0; float aev = 0.f, lg = -1e30f;
        if(lane < nj){
            int pk = packed[j0+lane];
            sj  = pk & 0x1FFFF;
            aev = Tl[pk >> 17];
            lg  = lrelu(as_[sj] + adv + aev);
        }
        float cm = lg, sa = aev;
        #pragma unroll
        for(int off=32; off; off>>=1){ cm = fmaxf(cm, __shfl_xor(cm,off,64)); sa += __shfl_xor(sa,off,64); }
        sumae += sa;
        float nm = fmaxf(m, cm);
        float w = (lane<nj) ? expf(lg-nm) : 0.f;
        float ws = w;
        #pragma unroll
        for(int off=32; off; off>>=1) ws += __shfl_xor(ws,off,64);
        float scale = (m > -1e29f) ? expf(m-nm) : 0.f;
        d = d*scale + ws;
        a0*=scale; a1*=scale; a2*=scale; a3*=scale;
        int j = 0;
        for(; j+3<nj; j+=4){
            a0 = fmaf(bcastf(w,j+0), h[(size_t)__builtin_amdgcn_readlane(sj,j+0)*64 + lane], a0);
            a1 = fmaf(bcastf(w,j+1), h[(size_t)__builtin_amdgcn_readlane(sj,j+1)*64 + lane], a1);
            a2 = fmaf(bcastf(w,j+2), h[(size_t)__builtin_amdgcn_readlane(sj,j+2)*64 + lane], a2);
            a3 = fmaf(bcastf(w,j+3), h[(size_t)__builtin_amdgcn_readlane(sj,j+3)*64 + lane], a3);
        }
        for(; j<nj; j++)
            a0 = fmaf(bcastf(w,j), h[(size_t)__builtin_amdgcn_readlane(sj,j)*64 + lane], a0);
        m = nm;
    }
    int deg = e - b;
    float ael = sumae / fmaxf((float)deg, 1.f);
    float ls = lrelu(as_[node] + adv + ael);
    float nm = fmaxf(m, ls);
    float scale = (m > -1e29f) ? expf(m-nm) : 0.f;
    float wl = expf(ls-nm);
    d = d*scale + wl;
    float acc = (a0+a1)+(a2+a3);
    acc = acc*scale + wl*h[(size_t)node*64 + lane];
    o[(size_t)node*64 + lane] = acc/d + bias[lane];
}

// ---------------- dense: lane=channel, wave owns 4 nodes, no LDS, no barriers ----------------

__global__ __launch_bounds__(256) void k_dense(
    const float* __restrict__ o,
    const float* __restrict__ W1, const float* __restrict__ b1,
    const float* __restrict__ W2, const float* __restrict__ b2,
    const float* __restrict__ W3, const float* __restrict__ b3,
    float* __restrict__ bestF, float* __restrict__ bestMs, int layer,
    const float* __restrict__ Wn, const float* __restrict__ atts, const float* __restrict__ attd,
    float* __restrict__ hn, float* __restrict__ asn, float* __restrict__ adn_,
    const float* __restrict__ A, const float* __restrict__ g1b1,
    const float* __restrict__ w2, const float* __restrict__ g1b2,
    const float* __restrict__ B, const float* __restrict__ g2b1,
    const float* __restrict__ C, const float* __restrict__ g2b2,
    float* __restrict__ h1, float* __restrict__ h2,
    int n, int last)
{
    int t = threadIdx.x, lane = t & 63;
    int base = blockIdx.x*16 + (t>>6)*4;
    if(base >= n) return;
    int nv = min(4, n - base);

    // ---- load o rows: lane = channel
    float ov[4];
    #pragma unroll
    for(int nn=0;nn<4;nn++) ov[nn] = (nn<nv) ? o[(size_t)(base+nn)*64 + lane] : 0.f;

    // ---- B: t1 = relu(o @ W1 + b1)
    float t1[4];
    {
        float bb = b1[lane];
        #pragma unroll
        for(int nn=0;nn<4;nn++) t1[nn] = bb;
        #pragma unroll 8
        for(int k=0;k<64;k++){
            float w = W1[k*64 + lane];
            #pragma unroll
            for(int nn=0;nn<4;nn++) t1[nn] = fmaf(bcastf(ov[nn],k), w, t1[nn]);
        }
        #pragma unroll
        for(int nn=0;nn<4;nn++) t1[nn] = fmaxf(t1[nn], 0.f);
    }

    // ---- C: t2 = relu(t1 @ W2 + b2)
    float t2[4];
    {
        float bb = b2[lane];
        #pragma unroll
        for(int nn=0;nn<4;nn++) t2[nn] = bb;
        #pragma unroll 8
        for(int k=0;k<64;k++){
            float w = W2[k*64 + lane];
            #pragma unroll
            for(int nn=0;nn<4;nn++) t2[nn] = fmaf(bcastf(t1[nn],k), w, t2[nn]);
        }
        #pragma unroll
        for(int nn=0;nn<4;nn++) t2[nn] = fmaxf(t2[nn], 0.f);
    }

    // ---- D: x' = t2 @ W3 + b3 (128 out: c=lane and c=lane+64)
    float xp0[4], xp1[4];
    {
        float ba = b3[lane], bb = b3[lane+64];
        #pragma unroll
        for(int nn=0;nn<4;nn++){ xp0[nn]=ba; xp1[nn]=bb; }
        #pragma unroll 4
        for(int k=0;k<64;k++){
            float wa = W3[k*128 + lane];
            float wb = W3[k*128 + 64 + lane];
            #pragma unroll
            for(int nn=0;nn<4;nn++){
                float s = bcastf(t2[nn],k);
                xp0[nn] = fmaf(s, wa, xp0[nn]);
                xp1[nn] = fmaf(s, wb, xp1[nn]);
            }
        }
    }

    // ---- JKN: ms per node, update decision
    float msv[4]; bool upd[4];
    #pragma unroll
    for(int nn=0;nn<4;nn++){
        float p = wsum(xp0[nn]*xp0[nn] + xp1[nn]*xp1[nn]);
        msv[nn] = p;
        float prev = -1e30f;
        if(layer > 0 && nn < nv) prev = bestMs[base+nn];
        upd[nn] = (layer==0) || (p > prev);
    }

    if(!last){
        #pragma unroll
        for(int nn=0;nn<4;nn++){
            if(nn<nv && upd[nn]){
                bestF[(size_t)(base+nn)*128 + lane]      = xp0[nn];
                bestF[(size_t)(base+nn)*128 + 64 + lane] = xp1[nn];
                if(lane==0) bestMs[base+nn] = msv[nn];
            }
        }
        // ---- F: h_next = x' @ Wn (k = 128)
        float hv[4] = {0,0,0,0};
        #pragma unroll 8
        for(int k=0;k<64;k++){
            float w = Wn[k*64 + lane];
            #pragma unroll
            for(int nn=0;nn<4;nn++) hv[nn] = fmaf(bcastf(xp0[nn],k), w, hv[nn]);
        }
        #pragma unroll 8
        for(int k=0;k<64;k++){
            float w = Wn[(k+64)*64 + lane];
            #pragma unroll
            for(int nn=0;nn<4;nn++) hv[nn] = fmaf(bcastf(xp1[nn],k), w, hv[nn]);
        }
        float atl = atts[lane], adl = attd[lane];
        #pragma unroll
        for(int nn=0;nn<4;nn++){
            float sa = wsum(hv[nn]*atl);
            float sd = wsum(hv[nn]*adl);
            if(nn<nv){
                hn[(size_t)(base+nn)*64 + lane] = hv[nn];
                if(lane==0){ asn[base+nn] = sa; adn_[base+nn] = sd; }
            }
        }
        return;
    }

    // ================= last layer: fused pooling, feature = upd ? x' : bestF =================
    #pragma unroll
    for(int nn=0;nn<4;nn++){
        if(nn<nv && !upd[nn]){
            xp0[nn] = bestF[(size_t)(base+nn)*128 + lane];
            xp1[nn] = bestF[(size_t)(base+nn)*128 + 64 + lane];
        }
    }
    // ---- P1: p1 = relu(F @ g1W1 + g1b1); h1 = p1 . g1W2 + g1b2
    {
        float p1[4];
        float bb = g1b1[lane];
        #pragma unroll
        for(int nn=0;nn<4;nn++) p1[nn] = bb;
        #pragma unroll 8
        for(int k=0;k<64;k++){
            float w = A[k*64 + lane];
            #pragma unroll
            for(int nn=0;nn<4;nn++) p1[nn] = fmaf(bcastf(xp0[nn],k), w, p1[nn]);
        }
        #pragma unroll 8
        for(int k=0;k<64;k++){
            float w = A[(k+64)*64 + lane];
            #pragma unroll
            for(int nn=0;nn<4;nn++) p1[nn] = fmaf(bcastf(xp1[nn],k), w, p1[nn]);
        }
        float w2l = w2[lane], bout = g1b2[0];
        #pragma unroll
        for(int nn=0;nn<4;nn++){
            float s = wsum(fmaxf(p1[nn],0.f)*w2l);
            if(nn<nv && lane==0) h1[base+nn] = s + bout;
        }
    }
    // ---- P2: p2 = relu(F @ g2W1 + g2b1)
    float p2[4];
    {
        float bb = g2b1[lane];
        #pragma unroll
        for(int nn=0;nn<4;nn++) p2[nn] = bb;
        #pragma unroll 8
        for(int k=0;k<64;k++){
            float w = B[k*64 + lane];
            #pragma unroll
            for(int nn=0;nn<4;nn++) p2[nn] = fmaf(bcastf(xp0[nn],k), w, p2[nn]);
        }
        #pragma unroll 8
        for(int k=0;k<64;k++){
            float w = B[(k+64)*64 + lane];
            #pragma unroll
            for(int nn=0;nn<4;nn++) p2[nn] = fmaf(bcastf(xp1[nn],k), w, p2[nn]);
        }
        #pragma unroll
        for(int nn=0;nn<4;nn++) p2[nn] = fmaxf(p2[nn], 0.f);
    }
    // ---- P3: h2 = p2 @ g2W2 + g2b2 (128 out)
    {
        float r0[4], r1[4];
        float ba = g2b2[lane], bb = g2b2[lane+64];
        #pragma unroll
        for(int nn=0;nn<4;nn++){ r0[nn]=ba; r1[nn]=bb; }
        #pragma unroll 4
        for(int k=0;k<64;k++){
            float wa = C[k*128 + lane];
            float wb = C[k*128 + 64 + lane];
            #pragma unroll
            for(int nn=0;nn<4;nn++){
                float s = bcastf(p2[nn],k);
                r0[nn] = fmaf(s, wa, r0[nn]);
                r1[nn] = fmaf(s, wb, r1[nn]);
            }
        }
        #pragma unroll
        for(int nn=0;nn<4;nn++){
            if(nn<nv){
                h2[(size_t)(base+nn)*128 + lane]      = r0[nn];
                h2[(size_t)(base+nn)*128 + 64 + lane] = r1[nn];
            }
        }
    }
}

// ---------------- pooling softmax + per-graph prediction MLP ----------------

__global__ __launch_bounds__(128) void k_pool2(const float* __restrict__ h1, const float* __restrict__ h2,
                      float* __restrict__ wbuf,
                      const float* __restrict__ pW1, const float* __restrict__ pb1,
                      const float* __restrict__ pW2, const float* __restrict__ pb2,
                      const float* __restrict__ pW3, const float* __restrict__ pb3,
                      float* __restrict__ out, int n, int G){
    __shared__ float sh[128];
    __shared__ float hgrow[128];
    int g = blockIdx.x, tid = threadIdx.x;
    int start = (g*n + G-1)/G, end = ((g+1)*n + G-1)/G;
    float lm = -1e30f;
    for(int i=start+tid; i<end; i+=128) lm = fmaxf(lm, h1[i]);
    sh[tid]=lm; __syncthreads();
    for(int off=64; off; off>>=1){ if(tid<off) sh[tid]=fmaxf(sh[tid],sh[tid+off]); __syncthreads(); }
    float m = sh[0]; __syncthreads();
    float lsum = 0.f;
    for(int i=start+tid; i<end; i+=128){ float w = expf(h1[i]-m); wbuf[i]=w; lsum+=w; }
    sh[tid]=lsum; __syncthreads();
    for(int off=64; off; off>>=1){ if(tid<off) sh[tid]+=sh[tid+off]; __syncthreads(); }
    float denom = sh[0];
    float a0=0.f,a1=0.f,a2=0.f,a3=0.f;
    int i = start;
    for(; i+3<end; i+=4){
        a0 = fmaf(wbuf[i+0], h2[(size_t)(i+0)*128 + tid], a0);
        a1 = fmaf(wbuf[i+1], h2[(size_t)(i+1)*128 + tid], a1);
        a2 = fmaf(wbuf[i+2], h2[(size_t)(i+2)*128 + tid], a2);
        a3 = fmaf(wbuf[i+3], h2[(size_t)(i+3)*128 + tid], a3);
    }
    for(; i<end; i++) a0 = fmaf(wbuf[i], h2[(size_t)i*128 + tid], a0);
    float acc = (a0+a1)+(a2+a3);
    hgrow[tid] = acc/denom/(float)(end-start);
    __syncthreads();
    if(tid < 64){
        float t1v = pb1[tid];
        for(int k=0;k<128;k++) t1v = fmaf(hgrow[k], pW1[k*64+tid], t1v);
        t1v = fmaxf(t1v, 0.f);
        float t2v = pb2[tid];
        for(int k=0;k<64;k++) t2v = fmaf(__shfl(t1v,k,64), pW2[k*64+tid], t2v);
        t2v = fmaxf(t2v, 0.f);
        float s = t2v * pW3[tid];
        #pragma unroll
        for(int off=32; off; off>>=1) s += __shfl_xor(s,off,64);
        if(tid==0) out[g] = s + pb3[0];
    }
}

extern "C" void kernel_launch(void* const* d_in, const int* in_sizes, int n_in,
                              void* d_out, int out_size, void* d_ws, size_t ws_size,
                              hipStream_t stream){
    const int*   x_idx   = (const int*)  d_in[0];
    const int*   eindex  = (const int*)  d_in[1];
    const int*   eattr   = (const int*)  d_in[2];
    const float* emb     = (const float*)d_in[4];
    const float* conv_W  = (const float*)d_in[5];
    const float* conv_We = (const float*)d_in[6];
    const float* att_src = (const float*)d_in[7];
    const float* att_dst = (const float*)d_in[8];
    const float* att_edg = (const float*)d_in[9];
    const float* conv_b  = (const float*)d_in[10];
    const float* mW1 = (const float*)d_in[11]; const float* mb1 = (const float*)d_in[12];
    const float* mW2 = (const float*)d_in[13]; const float* mb2 = (const float*)d_in[14];
    const float* mW3 = (const float*)d_in[15]; const float* mb3 = (const float*)d_in[16];
    const float* g1W1= (const float*)d_in[17]; const float* g1b1= (const float*)d_in[18];
    const float* g1W2= (const float*)d_in[19]; const float* g1b2= (const float*)d_in[20];
    const float* g2W1= (const float*)d_in[21]; const float* g2b1= (const float*)d_in[22];
    const float* g2W2= (const float*)d_in[23]; const float* g2b2= (const float*)d_in[24];
    const float* pW1 = (const float*)d_in[25]; const float* pb1 = (const float*)d_in[26];
    const float* pW2 = (const float*)d_in[27]; const float* pb2 = (const float*)d_in[28];
    const float* pW3 = (const float*)d_in[29]; const float* pb3 = (const float*)d_in[30];

    const int N = in_sizes[0];
    const int E = in_sizes[2];
    const int G = out_size;
    const int* src = eindex;
    const int* dst = eindex + E;
    const int NW = (N + 3) / 4;        // wave-per-node grid (gat, sortb)
    const int ND = (N + 15) / 16;      // 4-nodes-per-wave grids (hx, dense)

    char* p = (char*)d_ws;
    auto alloc = [&](size_t bytes)->void*{ void* r = (void*)p; p += (bytes + 255) & ~(size_t)255; return r; };
    float* h      = (float*)alloc((size_t)N*64*4);
    float* o      = (float*)alloc((size_t)N*64*4);
    float* bestF  = (float*)alloc((size_t)N*128*4);
    float* h2buf  = (float*)alloc((size_t)N*128*4);
    float* bestMs = (float*)alloc((size_t)N*4);
    float* as_    = (float*)alloc((size_t)N*4);
    float* ad_    = (float*)alloc((size_t)N*4);
    float* Tbuf   = (float*)alloc(6*128*4);
    float* h1     = (float*)alloc((size_t)N*4);
    int*   cnt    = (int*)  alloc((size_t)N*4);
    int*   cnt2   = (int*)  alloc((size_t)N*4);
    int*   rowptr = (int*)  alloc((size_t)(N+1)*4);
    int*   eid    = (int*)  alloc((size_t)E*4);
    int*   packed = (int*)  alloc((size_t)E*4);

    hipMemsetAsync(cnt,  0, (size_t)N*4, stream);
    hipMemsetAsync(cnt2, 0, (size_t)N*4, stream);

    k_count<<<(E+255)/256, 256, 0, stream>>>(dst, cnt, E);
    k_scan<<<1, 1024, 0, stream>>>(cnt, rowptr, N);
    k_scatter<<<(E+255)/256, 256, 0, stream>>>(dst, rowptr, cnt2, eid, E);
    k_sortb<<<NW, 256, 0, stream>>>(rowptr, eid, N);
    k_pack<<<(E+255)/256, 256, 0, stream>>>(eid, src, eattr, packed, E);
    k_table<<<1, 768, 0, stream>>>(conv_We, att_edg, emb, Tbuf);
    k_hx<<<ND, 256, 0, stream>>>(x_idx, emb, conv_W, att_src, att_dst, h, as_, ad_, N);

    for(int l=0; l<6; l++){
        int last = (l==5) ? 1 : 0;
        const float* Wn   = last ? conv_W  : conv_W  + (size_t)(l+1)*8192;
        const float* atsn = last ? att_src : att_src + (l+1)*64;
        const float* atdn = last ? att_dst : att_dst + (l+1)*64;
        k_gat<<<NW, 256, 0, stream>>>(h, as_, ad_, Tbuf + l*128, packed, rowptr, conv_b + l*64, o, N);
        k_dense<<<ND, 256, 0, stream>>>(o,
            mW1 + (size_t)l*4096, mb1 + l*64, mW2 + (size_t)l*4096, mb2 + l*64,
            mW3 + (size_t)l*8192, mb3 + l*128,
            bestF, bestMs, l,
            Wn, atsn, atdn,
            h, as_, ad_,
            g1W1, g1b1, g1W2, g1b2, g2W1, g2b1, g2W2, g2b2,
            h1, h2buf,
            N, last);
    }

    k_pool2<<<G, 128, 0, stream>>>(h1, h2buf, bestMs,
            pW1, pb1, pW2, pb2, pW3, pb3, (float*)d_out, N, G);
}